// Round 15
// baseline (323.402 us; speedup 1.0000x reference)
//
#include <hip/hip_runtime.h>
#include <math.h>

#define SDIM   256
#define HID    512
#define NH     5
#define HEADS  10
#define POP    4096
#define ITERS  4
#define ELITE  819
#define INIT_STDF 0.4f
#define MIN_STDF  0.1f

// ws layout (champion layout):
//   floats: base1[10][512] @0, q_part[2][10][4096] @5120, state @87040 (7 f)
//   bytes WS_W2S_BYTE+: W2S split/transposed weights, slab layout:
//   [h][cb(2)][jc(16)] slabs of 16384 ushorts: {hi[kg4][col256][ji8], lo[...]}
#define WS_BASE1 0
#define WS_Q     5120
#define WS_STATE 87040
#define WS_W2S_BYTE 348224
#define W2S_USHORTS (HEADS * 2 * 16 * 16384)
#define WS_NEED_BYTES (WS_W2S_BYTE + (size_t)W2S_USHORTS * 2)

typedef __attribute__((ext_vector_type(4))) float f32x4;
typedef __attribute__((ext_vector_type(8))) short bf16x8;

static __device__ __forceinline__ unsigned short bf16_rne(float x) {
    unsigned b = __float_as_uint(x);
    return (unsigned short)((b + 0x7FFFu + ((b >> 16) & 1u)) >> 16);
}

// packed f32x2 -> bf16x2 (hardware cvt_pk, RNE)
static __device__ __forceinline__ unsigned pack2(float x, float y) {
    unsigned r;
    asm("v_cvt_pk_bf16_f32 %0, %1, %2" : "=v"(r) : "v"(x), "v"(y));
    return r;
}

static __device__ __forceinline__ float clip1(float x) {
    return fminf(fmaxf(x, -1.f), 1.f);
}

// ---------------------------------------------------------------------------
// Kernel 1: base1[h][j] = b1[h][j] + sum_i s[i] * W1[h][i][j]; init state
// ---------------------------------------------------------------------------
__global__ __launch_bounds__(256) void k_base(const float* __restrict__ state,
                                              const float* __restrict__ W1,
                                              const float* __restrict__ b1,
                                              float* __restrict__ ws)
{
    const int h = blockIdx.y;
    const int j = blockIdx.x * 256 + threadIdx.x;
    const float* w1h = W1 + (size_t)h * 258 * HID;
    float acc = b1[h * HID + j];
    for (int i = 0; i < SDIM; ++i)
        acc += state[i] * w1h[(size_t)i * HID + j];
    ws[WS_BASE1 + h * HID + j] = acc;

    if (h == 0 && blockIdx.x == 0 && threadIdx.x == 0) {
        float* st = ws + WS_STATE;
        st[0] = 0.f; st[1] = 0.f;
        st[2] = INIT_STDF; st[3] = INIT_STDF;
        st[4] = 0.f; st[5] = 0.f;
        st[6] = -3.402823466e38f;
    }
}

// ---------------------------------------------------------------------------
// Kernel 1b: W2 -> W2S (transpose + RNE hi/lo split). Coalesced both sides.
// ---------------------------------------------------------------------------
__global__ __launch_bounds__(256) void k_split(const float* __restrict__ W2,
                                               unsigned short* __restrict__ W2S)
{
    const int h = blockIdx.z, cb = blockIdx.y, jc = blockIdx.x;
    const int c = threadIdx.x;
    unsigned short* slab = W2S + (size_t)((h * 2 + cb) * 16 + jc) * 16384;
    #pragma unroll
    for (int jg = 0; jg < 4; ++jg) {
        unsigned hp[4], lp[4];
        #pragma unroll
        for (int i = 0; i < 4; ++i) {
            const int j = jc * 32 + jg * 8 + 2 * i;
            float v0 = W2[(size_t)(h * HID + j) * HID + cb * 256 + c];
            float v1 = W2[(size_t)(h * HID + j + 1) * HID + cb * 256 + c];
            unsigned short h0 = bf16_rne(v0), h1 = bf16_rne(v1);
            float f0 = __uint_as_float((unsigned)h0 << 16);
            float f1 = __uint_as_float((unsigned)h1 << 16);
            unsigned short l0 = bf16_rne(v0 - f0), l1 = bf16_rne(v1 - f1);
            hp[i] = (unsigned)h0 | ((unsigned)h1 << 16);
            lp[i] = (unsigned)l0 | ((unsigned)l1 << 16);
        }
        uint4 HV, LV;
        HV.x = hp[0]; HV.y = hp[1]; HV.z = hp[2]; HV.w = hp[3];
        LV.x = lp[0]; LV.y = lp[1]; LV.z = lp[2]; LV.w = lp[3];
        *(uint4*)&slab[jg * 2048 + c * 8] = HV;
        *(uint4*)&slab[8192 + jg * 2048 + c * 8] = LV;
    }
}

// ---------------------------------------------------------------------------
// Kernel 2 (champion + BK=128): 512 thr / 8 waves = 64 rows x 256 cols,
// full K; grid 1280. Wave = 64 rows x 32 cols, acc[4][2] = 32 AGPR
// (unified ~92-108 <= 128 -> 4 waves/SIMD). FOUR 32-k chunks per barrier
// (4 barriers total, was 8 in R14, 16 in R12): each halving of rendezvous
// frequency measured +13-15% (70.5 -> 61.2 us) by letting resident waves
// drift so LDS/VALU/MFMA pipes mix across blocks instead of lockstep.
// A: 128-k tile computed into LDS dbuf (2x32KB) by all 512 threads with
// conflict-free pairing. B: direct global->VGPR, alternating register
// sets (Bc/Bn), always one chunk ahead. LDS 67.6 KB -> still 2 blocks/CU.
// Writes q_part[cb][h][row]; k_select sums the 2 partials.
// ---------------------------------------------------------------------------
__global__ __launch_bounds__(512, 4) void k_score_mfma14(
    const float* __restrict__ noise, const float* __restrict__ W1,
    const unsigned short* __restrict__ W2S,
    const float* __restrict__ b2, const float* __restrict__ W3,
    float* __restrict__ ws, int t)
{
    __shared__ unsigned short As[2][16384];  // dbuf of 128k tiles:
    // sub s (0..3) at s*4096: {hi[kg4][row64][ji8] @0, lo @+2048}
    __shared__ float red[8][64];

    const int tid = threadIdx.x;
    const int bid = blockIdx.x;
    // bijective XCD remap (1280 = 8*160): consecutive w share (h,cb) panel
    const int w = (bid & 7) * 160 + (bid >> 3);
    const int h = w >> 7;
    const int rem = w & 127;
    const int cb = rem >> 6;
    const int rs = rem & 63;            // row-stripe of 64

    const int lane = tid & 63;
    const int wv = tid >> 6;            // 0..7 -> 32-col strip
    const int l15 = lane & 15, lk = lane >> 4;

    // computeA role (all 512 threads, conflict-free pairing):
    // akg = tid>>7 (0..3), row = (tid>>1)&63, half4 = tid&1.
    const int akg = tid >> 7;
    const int arow = (tid >> 1) & 63;
    const int ahalf = tid & 1;

    const float* st = ws + WS_STATE;
    const float mu0 = st[0], mu1 = st[1], sd0 = st[2], sd1 = st[3];
    float2 e = *(const float2*)&noise[((size_t)t * POP + rs * 64 + arow) * 2];
    const float a0 = clip1(mu0 + sd0 * e.x);
    const float a1 = clip1(mu1 + sd1 * e.y);

    const float* base1 = ws + WS_BASE1 + h * HID;
    const float* w1u = W1 + ((size_t)h * 258 + 256) * HID;
    const float* w1v = W1 + ((size_t)h * 258 + 257) * HID;
    const unsigned short* bslab = W2S + (size_t)((h * 2 + cb) * 16) * 16384;
    // B frag: kg=lk, col = wv*32 + n*16 + l15 (lo at +8192)
    const int bco = lk * 2048 + (wv * 32 + l15) * 8;

    // compute A 128-k tile `it4` (rank-2 + relu + cvt_pk split) into As[buf]
    auto computeA = [&](int it4, int buf) {
        #pragma unroll
        for (int s = 0; s < 4; ++s) {
            const int j = it4 * 128 + s * 32 + akg * 8 + ahalf * 4;
            f32x4 b0 = *(const f32x4*)&base1[j];
            f32x4 u0 = *(const f32x4*)&w1u[j];
            f32x4 v0 = *(const f32x4*)&w1v[j];
            float hv[4];
            #pragma unroll
            for (int i = 0; i < 4; ++i)
                hv[i] = fmaxf(b0[i] + a0 * u0[i] + a1 * v0[i], 0.f);
            unsigned ph[2], pl[2];
            #pragma unroll
            for (int i = 0; i < 2; ++i) {
                ph[i] = pack2(hv[2 * i], hv[2 * i + 1]);
                float fx = __uint_as_float(ph[i] << 16);
                float fy = __uint_as_float(ph[i] & 0xFFFF0000u);
                pl[i] = pack2(hv[2 * i] - fx, hv[2 * i + 1] - fy);
            }
            uint2 HV, LV;
            HV.x = ph[0]; HV.y = ph[1];
            LV.x = pl[0]; LV.y = pl[1];
            const int ao = s * 4096 + akg * 512 + arow * 8 + ahalf * 4;
            *(uint2*)&As[buf][ao] = HV;
            *(uint2*)&As[buf][2048 + ao] = LV;
        }
    };

    f32x4 acc[4][2];
    #pragma unroll
    for (int m = 0; m < 4; ++m)
        #pragma unroll
        for (int n = 0; n < 2; ++n)
            acc[m][n] = (f32x4){0.f, 0.f, 0.f, 0.f};

    // prologue: A tile 0 into buf 0; B chunk 0 into Bc
    computeA(0, 0);
    bf16x8 BcH[2], BcL[2], BnH[2], BnL[2];
    #pragma unroll
    for (int n = 0; n < 2; ++n) {
        BcH[n] = *(const bf16x8*)(bslab + bco + n * 128);
        BcL[n] = *(const bf16x8*)(bslab + 8192 + bco + n * 128);
    }
    __syncthreads();

    // one sub-step: A frags at aoff, MFMA with (UH,UL), prefetch chunk nch
    // into (PH,PL). Alternating register sets avoid rotation copies; WAR is
    // safe because the prefetch is issued after the consuming MFMAs in
    // program order (scoreboard holds the write until reads complete).
#define SUBSTEP(AOFF, UH, UL, PH, PL, NCH)                                    \
    {                                                                         \
        bf16x8 AH[4], AL[4];                                                  \
        _Pragma("unroll")                                                     \
        for (int m = 0; m < 4; ++m) {                                         \
            const int ad = (AOFF) + lk * 512 + (m * 16 + l15) * 8;            \
            AH[m] = *(const bf16x8*)&As[cur][ad];                             \
            AL[m] = *(const bf16x8*)&As[cur][2048 + ad];                      \
        }                                                                     \
        {                                                                     \
            const unsigned short* bp = bslab + (size_t)(NCH) * 16384;         \
            _Pragma("unroll")                                                 \
            for (int n = 0; n < 2; ++n) {                                     \
                PH[n] = *(const bf16x8*)(bp + bco + n * 128);                 \
                PL[n] = *(const bf16x8*)(bp + 8192 + bco + n * 128);          \
            }                                                                 \
        }                                                                     \
        __builtin_amdgcn_s_setprio(1);                                        \
        _Pragma("unroll")                                                     \
        for (int m = 0; m < 4; ++m)                                           \
            _Pragma("unroll")                                                 \
            for (int n = 0; n < 2; ++n)                                       \
                acc[m][n] = __builtin_amdgcn_mfma_f32_16x16x32_bf16(          \
                    AH[m], UH[n], acc[m][n], 0, 0, 0);                        \
        _Pragma("unroll")                                                     \
        for (int m = 0; m < 4; ++m)                                           \
            _Pragma("unroll")                                                 \
            for (int n = 0; n < 2; ++n)                                       \
                acc[m][n] = __builtin_amdgcn_mfma_f32_16x16x32_bf16(          \
                    AL[m], UH[n], acc[m][n], 0, 0, 0);                        \
        _Pragma("unroll")                                                     \
        for (int m = 0; m < 4; ++m)                                           \
            _Pragma("unroll")                                                 \
            for (int n = 0; n < 2; ++n)                                       \
                acc[m][n] = __builtin_amdgcn_mfma_f32_16x16x32_bf16(          \
                    AH[m], UL[n], acc[m][n], 0, 0, 0);                        \
        __builtin_amdgcn_s_setprio(0);                                        \
    }

    int cur = 0;
    #pragma unroll 1
    for (int it = 0; it < 4; ++it) {
        const int c0 = it * 4;
        SUBSTEP(0,     BcH, BcL, BnH, BnL, c0 + 1)
        SUBSTEP(4096,  BnH, BnL, BcH, BcL, c0 + 2)
        SUBSTEP(8192,  BcH, BcL, BnH, BnL, c0 + 3)
        SUBSTEP(12288, BnH, BnL, BcH, BcL, (it < 3) ? c0 + 4 : 15)
        // next 128-k A tile, then the single barrier of this iteration
        computeA((it < 3) ? it + 1 : 3, cur ^ 1);
        __syncthreads();
        cur ^= 1;
    }
#undef SUBSTEP

    // epilogue: q_part = sum over this block's 256 cols of
    //           relu(acc + b2[col]) * W3[col]
    // C layout (m89): col = l15, row = lk*4 + reg (+16 per m-frag)
    float qp[4][4];
    #pragma unroll
    for (int m = 0; m < 4; ++m)
        #pragma unroll
        for (int r = 0; r < 4; ++r) qp[m][r] = 0.f;
    #pragma unroll
    for (int n = 0; n < 2; ++n) {
        int gcol = cb * 256 + wv * 32 + n * 16 + l15;
        float b2v = b2[h * HID + gcol];
        float w3v = W3[h * HID + gcol];
        #pragma unroll
        for (int m = 0; m < 4; ++m)
            #pragma unroll
            for (int r = 0; r < 4; ++r)
                qp[m][r] += fmaxf(acc[m][n][r] + b2v, 0.f) * w3v;
    }
    #pragma unroll
    for (int m = 0; m < 4; ++m)
        #pragma unroll
        for (int r = 0; r < 4; ++r) {
            float v = qp[m][r];
            v += __shfl_xor(v, 1);
            v += __shfl_xor(v, 2);
            v += __shfl_xor(v, 4);
            v += __shfl_xor(v, 8);
            if (l15 == 0) red[wv][m * 16 + lk * 4 + r] = v;
        }
    __syncthreads();
    if (tid < 64) {
        float q = 0.f;
        #pragma unroll
        for (int s = 0; s < 8; ++s) q += red[s][tid];
        ws[WS_Q + (size_t)(cb * HEADS + h) * POP + rs * 64 + tid] = q;
    }
}

// ---------------------------------------------------------------------------
// Kernel 2 (fp32 fallback, used only if ws too small): writes part0, zeroes
// part1 so k_select's partial-sum read stays correct.
// ---------------------------------------------------------------------------
__global__ __launch_bounds__(256) void k_score(const float* __restrict__ noise,
                                               const float* __restrict__ W1,
                                               const float* __restrict__ W2,
                                               const float* __restrict__ b2,
                                               const float* __restrict__ W3,
                                               float* __restrict__ ws, int t)
{
    __shared__ float h1[32][HID];
    __shared__ float a0s[32], a1s[32];
    __shared__ float red[2][16][2];

    const int tid = threadIdx.x;
    const int h   = blockIdx.y;
    const int p0  = blockIdx.x * 32;

    if (tid < 32) {
        const float* st = ws + WS_STATE;
        const int p = p0 + tid;
        float e0 = noise[((size_t)t * POP + p) * 2 + 0];
        float e1 = noise[((size_t)t * POP + p) * 2 + 1];
        a0s[tid] = fminf(fmaxf(st[0] + st[2] * e0, -1.f), 1.f);
        a1s[tid] = fminf(fmaxf(st[1] + st[3] * e1, -1.f), 1.f);
    }
    __syncthreads();

    const float* base1 = ws + WS_BASE1 + h * HID;
    const float* w1u = W1 + ((size_t)h * 258 + 256) * HID;
    const float* w1v = W1 + ((size_t)h * 258 + 257) * HID;
    #pragma unroll
    for (int jj = 0; jj < 2; ++jj) {
        int j = tid + jj * 256;
        float bb = base1[j], uu = w1u[j], vv = w1v[j];
        #pragma unroll
        for (int p = 0; p < 32; ++p)
            h1[p][j] = fmaxf(bb + a0s[p] * uu + a1s[p] * vv, 0.f);
    }
    __syncthreads();

    const int pg = tid >> 7;
    const int kl = tid & 127;
    const float* W2h = W2 + (size_t)h * HID * HID + kl;

    float acc[16][4];
    #pragma unroll
    for (int p = 0; p < 16; ++p)
        #pragma unroll
        for (int dk = 0; dk < 4; ++dk) acc[p][dk] = 0.f;

    for (int j0 = 0; j0 < HID; j0 += 4) {
        float w[4][4];
        #pragma unroll
        for (int dj = 0; dj < 4; ++dj)
            #pragma unroll
            for (int dk = 0; dk < 4; ++dk)
                w[dj][dk] = W2h[(size_t)(j0 + dj) * HID + dk * 128];
        #pragma unroll
        for (int p = 0; p < 16; ++p) {
            const float4 hv = *(const float4*)&h1[pg * 16 + p][j0];
            #pragma unroll
            for (int dk = 0; dk < 4; ++dk)
                acc[p][dk] += hv.x * w[0][dk] + hv.y * w[1][dk]
                            + hv.z * w[2][dk] + hv.w * w[3][dk];
        }
    }

    float b2v[4], w3v[4];
    #pragma unroll
    for (int dk = 0; dk < 4; ++dk) {
        b2v[dk] = b2[h * HID + kl + dk * 128];
        w3v[dk] = W3[h * HID + kl + dk * 128];
    }
    const int wid  = tid >> 6;
    const int lane = tid & 63;
    const int wig  = wid & 1;
    #pragma unroll
    for (int p = 0; p < 16; ++p) {
        float v = 0.f;
        #pragma unroll
        for (int dk = 0; dk < 4; ++dk)
            v += fmaxf(acc[p][dk] + b2v[dk], 0.f) * w3v[dk];
        #pragma unroll
        for (int off = 32; off; off >>= 1) v += __shfl_down(v, off);
        if (lane == 0) red[pg][p][wig] = v;
    }
    __syncthreads();
    if (tid < 32) {
        int pp = tid & 15, g = tid >> 4;
        ws[WS_Q + (size_t)h * POP + p0 + g * 16 + pp] =
            red[g][pp][0] + red[g][pp][1];
        ws[WS_Q + (size_t)(HEADS + h) * POP + p0 + g * 16 + pp] = 0.f;
    }
}

// ---------------------------------------------------------------------------
// Kernel 3 (1024 threads): scores from 2 q partials (+b3), exact top-819
// radix select, elite mean/std (ddof=1, double accum), best_a update.
// ---------------------------------------------------------------------------
__global__ __launch_bounds__(1024) void k_select(const float* __restrict__ noise,
                                                 const float* __restrict__ b3,
                                                 float* __restrict__ ws,
                                                 float* __restrict__ out, int t)
{
    __shared__ float    sc[POP];
    __shared__ unsigned uk[POP];
    __shared__ unsigned hist[256];
    __shared__ int      scan2[1024];
    __shared__ float    rf[1024];
    __shared__ int      ri_[1024];
    __shared__ double   rd[1024];
    __shared__ unsigned s_prefix;
    __shared__ int      s_r;

    const int tid = threadIdx.x;
    const float* q = ws + WS_Q;
    float* st = ws + WS_STATE;
    const float mu0 = st[0], mu1 = st[1], sd0 = st[2], sd1 = st[3];

    // scores = mean_h min(q1,q2); q[h] = part0 + part1 + b3[h]
    {
        const int p = tid * 4;
        f32x4 s = (f32x4){0.f, 0.f, 0.f, 0.f};
        #pragma unroll
        for (int hh = 0; hh < NH; ++hh) {
            f32x4 qa0 = *(const f32x4*)&q[(size_t)hh * POP + p];
            f32x4 qa1 = *(const f32x4*)&q[(size_t)(HEADS + hh) * POP + p];
            f32x4 qb0 = *(const f32x4*)&q[(size_t)(NH + hh) * POP + p];
            f32x4 qb1 = *(const f32x4*)&q[(size_t)(HEADS + NH + hh) * POP + p];
            float ba = b3[hh], bb = b3[NH + hh];
            #pragma unroll
            for (int i = 0; i < 4; ++i)
                s[i] += fminf(qa0[i] + qa1[i] + ba, qb0[i] + qb1[i] + bb);
        }
        #pragma unroll
        for (int i = 0; i < 4; ++i) {
            float v = s[i] * 0.2f;
            sc[p + i] = v;
            unsigned b = __float_as_uint(v);
            uk[p + i] = (b & 0x80000000u) ? ~b : (b | 0x80000000u);
        }
    }
    __syncthreads();

    // max + argmax (lowest index on ties)
    float mv = -3.402823466e38f; int mi = 0;
    #pragma unroll
    for (int k = 0; k < 4; ++k) {
        const int p = tid * 4 + k;
        float v = sc[p];
        if (v > mv) { mv = v; mi = p; }
    }
    rf[tid] = mv; ri_[tid] = mi;
    __syncthreads();
    for (int off = 512; off; off >>= 1) {
        if (tid < off) {
            float ov = rf[tid + off]; int oi = ri_[tid + off];
            if (ov > rf[tid] || (ov == rf[tid] && oi < ri_[tid])) {
                rf[tid] = ov; ri_[tid] = oi;
            }
        }
        __syncthreads();
    }
    const float maxsc = rf[0];
    const int argmax = ri_[0];
    __syncthreads();

    // radix select with parallel suffix-scan digit pick
    unsigned prefix = 0; int r = ELITE;
    for (int shift = 24; shift >= 0; shift -= 8) {
        if (tid < 256) hist[tid] = 0;
        __syncthreads();
        const unsigned himask = (shift < 24) ? (0xFFFFFFFFu << (shift + 8)) : 0u;
        for (int p = tid; p < POP; p += 1024) {
            unsigned key = uk[p];
            if ((key & himask) == prefix)
                atomicAdd(&hist[(key >> shift) & 255u], 1u);
        }
        __syncthreads();
        scan2[tid] = (tid < 256) ? (int)hist[tid] : 0;
        __syncthreads();
        for (int off = 1; off < 256; off <<= 1) {
            int v = (tid < 256 && tid + off < 256) ? scan2[tid + off] : 0;
            __syncthreads();
            if (tid < 256) scan2[tid] += v;
            __syncthreads();
        }
        if (tid < 256) {
            int above = (tid < 255) ? scan2[tid + 1] : 0;
            if (scan2[tid] >= r && above < r) {
                s_prefix = prefix | ((unsigned)tid << shift);
                s_r = r - above;
            }
        }
        __syncthreads();
        prefix = s_prefix; r = s_r;
        __syncthreads();
    }
    const unsigned uT = prefix;
    const int take = r;

    // tie ranks (index order) via prefix scan over contiguous 4-chunks
    int tieloc = 0;
    {
        const int base = tid * 4;
        #pragma unroll
        for (int k = 0; k < 4; ++k) if (uk[base + k] == uT) tieloc++;
    }
    scan2[tid] = tieloc;
    __syncthreads();
    for (int off = 1; off < 1024; off <<= 1) {
        int v = (tid >= off) ? scan2[tid - off] : 0;
        __syncthreads();
        scan2[tid] += v;
        __syncthreads();
    }
    const int tieExcl = scan2[tid] - tieloc;

    double s0 = 0, s1 = 0, ss0 = 0, ss1 = 0;
    {
        const int base = tid * 4;
        int trank = tieExcl;
        #pragma unroll
        for (int k = 0; k < 4; ++k) {
            const int p = base + k;
            const unsigned key = uk[p];
            bool inc = false;
            if (key > uT) inc = true;
            else if (key == uT) { if (trank < take) inc = true; trank++; }
            if (inc) {
                float e0 = noise[((size_t)t * POP + p) * 2 + 0];
                float e1 = noise[((size_t)t * POP + p) * 2 + 1];
                float a0 = fminf(fmaxf(mu0 + sd0 * e0, -1.f), 1.f);
                float a1 = fminf(fmaxf(mu1 + sd1 * e1, -1.f), 1.f);
                s0 += a0; s1 += a1;
                ss0 += (double)a0 * a0; ss1 += (double)a1 * a1;
            }
        }
    }
    double S0, S1, SS0, SS1;
    rd[tid] = s0;  __syncthreads();
    for (int off = 512; off; off >>= 1) { if (tid < off) rd[tid] += rd[tid + off]; __syncthreads(); }
    S0 = rd[0]; __syncthreads();
    rd[tid] = s1;  __syncthreads();
    for (int off = 512; off; off >>= 1) { if (tid < off) rd[tid] += rd[tid + off]; __syncthreads(); }
    S1 = rd[0]; __syncthreads();
    rd[tid] = ss0; __syncthreads();
    for (int off = 512; off; off >>= 1) { if (tid < off) rd[tid] += rd[tid + off]; __syncthreads(); }
    SS0 = rd[0]; __syncthreads();
    rd[tid] = ss1; __syncthreads();
    for (int off = 512; off; off >>= 1) { if (tid < off) rd[tid] += rd[tid + off]; __syncthreads(); }
    SS1 = rd[0]; __syncthreads();

    if (tid == 0) {
        const double n = (double)ELITE;
        double m0 = S0 / n, m1 = S1 / n;
        double v0 = (SS0 - S0 * S0 / n) / (n - 1.0);
        double v1 = (SS1 - S1 * S1 / n) / (n - 1.0);
        float nsd0 = fmaxf((float)sqrt(fmax(v0, 0.0)), MIN_STDF);
        float nsd1 = fmaxf((float)sqrt(fmax(v1, 0.0)), MIN_STDF);
        float e0 = noise[((size_t)t * POP + argmax) * 2 + 0];
        float e1 = noise[((size_t)t * POP + argmax) * 2 + 1];
        float a0 = fminf(fmaxf(mu0 + sd0 * e0, -1.f), 1.f);
        float a1 = fminf(fmaxf(mu1 + sd1 * e1, -1.f), 1.f);
        if (maxsc > st[6]) { st[4] = a0; st[5] = a1; st[6] = maxsc; }
        st[0] = (float)m0; st[1] = (float)m1; st[2] = nsd0; st[3] = nsd1;
        if (t == ITERS - 1) { out[0] = st[4]; out[1] = st[5]; }
    }
}

// ---------------------------------------------------------------------------
extern "C" void kernel_launch(void* const* d_in, const int* in_sizes, int n_in,
                              void* d_out, int out_size, void* d_ws, size_t ws_size,
                              hipStream_t stream)
{
    const float* state = (const float*)d_in[0];
    const float* noise = (const float*)d_in[1];
    const float* W1    = (const float*)d_in[2];
    const float* b1    = (const float*)d_in[3];
    const float* W2    = (const float*)d_in[4];
    const float* b2    = (const float*)d_in[5];
    const float* W3    = (const float*)d_in[6];
    const float* b3    = (const float*)d_in[7];
    float* out = (float*)d_out;
    float* ws  = (float*)d_ws;

    const bool fast = ws_size >= WS_NEED_BYTES;

    k_base<<<dim3(2, HEADS), 256, 0, stream>>>(state, W1, b1, ws);
    if (fast) {
        unsigned short* W2S = (unsigned short*)((char*)d_ws + WS_W2S_BYTE);
        k_split<<<dim3(16, 2, HEADS), 256, 0, stream>>>(W2, W2S);
        for (int t = 0; t < ITERS; ++t) {
            k_score_mfma14<<<dim3(1280), 512, 0, stream>>>(
                noise, W1, W2S, b2, W3, ws, t);
            k_select<<<1, 1024, 0, stream>>>(noise, b3, ws, out, t);
        }
    } else {
        for (int t = 0; t < ITERS; ++t) {
            k_score<<<dim3(POP / 32, HEADS), 256, 0, stream>>>(noise, W1, W2, b2, W3, ws, t);
            k_select<<<1, 1024, 0, stream>>>(noise, b3, ws, out, t);
        }
    }
}

// Round 16
// 294.966 us; speedup vs baseline: 1.0964x; 1.0964x over previous
//
#include <hip/hip_runtime.h>
#include <math.h>

#define SDIM   256
#define HID    512
#define NH     5
#define HEADS  10
#define POP    4096
#define ITERS  4
#define ELITE  819
#define INIT_STDF 0.4f
#define MIN_STDF  0.1f

// ws layout (champion layout):
//   floats: base1[10][512] @0, q_part[2][10][4096] @5120, state @87040 (7 f)
//   bytes WS_W2S_BYTE+: W2S split/transposed weights, slab layout:
//   [h][cb(2)][jc(16)] slabs of 16384 ushorts: {hi[kg4][col256][ji8], lo[...]}
#define WS_BASE1 0
#define WS_Q     5120
#define WS_STATE 87040
#define WS_W2S_BYTE 348224
#define W2S_USHORTS (HEADS * 2 * 16 * 16384)
#define WS_NEED_BYTES (WS_W2S_BYTE + (size_t)W2S_USHORTS * 2)

typedef __attribute__((ext_vector_type(4))) float f32x4;
typedef __attribute__((ext_vector_type(8))) short bf16x8;

static __device__ __forceinline__ unsigned short bf16_rne(float x) {
    unsigned b = __float_as_uint(x);
    return (unsigned short)((b + 0x7FFFu + ((b >> 16) & 1u)) >> 16);
}

// packed f32x2 -> bf16x2 (hardware cvt_pk, RNE)
static __device__ __forceinline__ unsigned pack2(float x, float y) {
    unsigned r;
    asm("v_cvt_pk_bf16_f32 %0, %1, %2" : "=v"(r) : "v"(x), "v"(y));
    return r;
}

static __device__ __forceinline__ float clip1(float x) {
    return fminf(fmaxf(x, -1.f), 1.f);
}

// ---------------------------------------------------------------------------
// Kernel 1: base1[h][j] = b1[h][j] + sum_i s[i] * W1[h][i][j]; init state
// ---------------------------------------------------------------------------
__global__ __launch_bounds__(256) void k_base(const float* __restrict__ state,
                                              const float* __restrict__ W1,
                                              const float* __restrict__ b1,
                                              float* __restrict__ ws)
{
    const int h = blockIdx.y;
    const int j = blockIdx.x * 256 + threadIdx.x;
    const float* w1h = W1 + (size_t)h * 258 * HID;
    float acc = b1[h * HID + j];
    for (int i = 0; i < SDIM; ++i)
        acc += state[i] * w1h[(size_t)i * HID + j];
    ws[WS_BASE1 + h * HID + j] = acc;

    if (h == 0 && blockIdx.x == 0 && threadIdx.x == 0) {
        float* st = ws + WS_STATE;
        st[0] = 0.f; st[1] = 0.f;
        st[2] = INIT_STDF; st[3] = INIT_STDF;
        st[4] = 0.f; st[5] = 0.f;
        st[6] = -3.402823466e38f;
    }
}

// ---------------------------------------------------------------------------
// Kernel 1b: W2 -> W2S (transpose + RNE hi/lo split). Coalesced both sides.
// ---------------------------------------------------------------------------
__global__ __launch_bounds__(256) void k_split(const float* __restrict__ W2,
                                               unsigned short* __restrict__ W2S)
{
    const int h = blockIdx.z, cb = blockIdx.y, jc = blockIdx.x;
    const int c = threadIdx.x;
    unsigned short* slab = W2S + (size_t)((h * 2 + cb) * 16 + jc) * 16384;
    #pragma unroll
    for (int jg = 0; jg < 4; ++jg) {
        unsigned hp[4], lp[4];
        #pragma unroll
        for (int i = 0; i < 4; ++i) {
            const int j = jc * 32 + jg * 8 + 2 * i;
            float v0 = W2[(size_t)(h * HID + j) * HID + cb * 256 + c];
            float v1 = W2[(size_t)(h * HID + j + 1) * HID + cb * 256 + c];
            unsigned short h0 = bf16_rne(v0), h1 = bf16_rne(v1);
            float f0 = __uint_as_float((unsigned)h0 << 16);
            float f1 = __uint_as_float((unsigned)h1 << 16);
            unsigned short l0 = bf16_rne(v0 - f0), l1 = bf16_rne(v1 - f1);
            hp[i] = (unsigned)h0 | ((unsigned)h1 << 16);
            lp[i] = (unsigned)l0 | ((unsigned)l1 << 16);
        }
        uint4 HV, LV;
        HV.x = hp[0]; HV.y = hp[1]; HV.z = hp[2]; HV.w = hp[3];
        LV.x = lp[0]; LV.y = lp[1]; LV.z = lp[2]; LV.w = lp[3];
        *(uint4*)&slab[jg * 2048 + c * 8] = HV;
        *(uint4*)&slab[8192 + jg * 2048 + c * 8] = LV;
    }
}

// ---------------------------------------------------------------------------
// Kernel 2 (R14 champion, BK=64): 512 thr / 8 waves = 64 rows x 256 cols,
// full K; grid 1280. Wave = 64 rows x 32 cols, acc[4][2] = 32 AGPR
// (unified ~92 <= 128 -> 4 waves/SIMD). Two 32-k chunks per barrier.
// ---------------------------------------------------------------------------
__global__ __launch_bounds__(512, 4) void k_score_mfma13(
    const float* __restrict__ noise, const float* __restrict__ W1,
    const unsigned short* __restrict__ W2S,
    const float* __restrict__ b2, const float* __restrict__ W3,
    float* __restrict__ ws, int t)
{
    __shared__ unsigned short As[2][8192];   // dbuf of 64k tiles
    __shared__ float red[8][64];

    const int tid = threadIdx.x;
    const int bid = blockIdx.x;
    const int w = (bid & 7) * 160 + (bid >> 3);
    const int h = w >> 7;
    const int rem = w & 127;
    const int cb = rem >> 6;
    const int rs = rem & 63;

    const int lane = tid & 63;
    const int wv = tid >> 6;
    const int l15 = lane & 15, lk = lane >> 4;

    const int akg = tid >> 7;
    const int arow = (tid >> 1) & 63;
    const int ahalf = tid & 1;

    const float* st = ws + WS_STATE;
    const float mu0 = st[0], mu1 = st[1], sd0 = st[2], sd1 = st[3];
    float2 e = *(const float2*)&noise[((size_t)t * POP + rs * 64 + arow) * 2];
    const float a0 = clip1(mu0 + sd0 * e.x);
    const float a1 = clip1(mu1 + sd1 * e.y);

    const float* base1 = ws + WS_BASE1 + h * HID;
    const float* w1u = W1 + ((size_t)h * 258 + 256) * HID;
    const float* w1v = W1 + ((size_t)h * 258 + 257) * HID;
    const unsigned short* bslab = W2S + (size_t)((h * 2 + cb) * 16) * 16384;
    const int bco = lk * 2048 + (wv * 32 + l15) * 8;

    auto computeA = [&](int it8, int buf) {
        #pragma unroll
        for (int s = 0; s < 2; ++s) {
            const int j = it8 * 64 + s * 32 + akg * 8 + ahalf * 4;
            f32x4 b0 = *(const f32x4*)&base1[j];
            f32x4 u0 = *(const f32x4*)&w1u[j];
            f32x4 v0 = *(const f32x4*)&w1v[j];
            float hv[4];
            #pragma unroll
            for (int i = 0; i < 4; ++i)
                hv[i] = fmaxf(b0[i] + a0 * u0[i] + a1 * v0[i], 0.f);
            unsigned ph[2], pl[2];
            #pragma unroll
            for (int i = 0; i < 2; ++i) {
                ph[i] = pack2(hv[2 * i], hv[2 * i + 1]);
                float fx = __uint_as_float(ph[i] << 16);
                float fy = __uint_as_float(ph[i] & 0xFFFF0000u);
                pl[i] = pack2(hv[2 * i] - fx, hv[2 * i + 1] - fy);
            }
            uint2 HV, LV;
            HV.x = ph[0]; HV.y = ph[1];
            LV.x = pl[0]; LV.y = pl[1];
            const int ao = s * 4096 + akg * 512 + arow * 8 + ahalf * 4;
            *(uint2*)&As[buf][ao] = HV;
            *(uint2*)&As[buf][2048 + ao] = LV;
        }
    };

    f32x4 acc[4][2];
    #pragma unroll
    for (int m = 0; m < 4; ++m)
        #pragma unroll
        for (int n = 0; n < 2; ++n)
            acc[m][n] = (f32x4){0.f, 0.f, 0.f, 0.f};

    computeA(0, 0);
    bf16x8 BcH[2], BcL[2], BnH[2], BnL[2];
    #pragma unroll
    for (int n = 0; n < 2; ++n) {
        BcH[n] = *(const bf16x8*)(bslab + bco + n * 128);
        BcL[n] = *(const bf16x8*)(bslab + 8192 + bco + n * 128);
    }
    __syncthreads();

    int cur = 0;
    #pragma unroll 1
    for (int it = 0; it < 8; ++it) {
        // ---------- sub 0: chunk 2it (A half 0, B = Bc) ----------
        bf16x8 AH[4], AL[4];
        #pragma unroll
        for (int m = 0; m < 4; ++m) {
            const int ad = lk * 512 + (m * 16 + l15) * 8;
            AH[m] = *(const bf16x8*)&As[cur][ad];
            AL[m] = *(const bf16x8*)&As[cur][2048 + ad];
        }
        {
            const unsigned short* bp = bslab + (size_t)(it * 2 + 1) * 16384;
            #pragma unroll
            for (int n = 0; n < 2; ++n) {
                BnH[n] = *(const bf16x8*)(bp + bco + n * 128);
                BnL[n] = *(const bf16x8*)(bp + 8192 + bco + n * 128);
            }
        }
        __builtin_amdgcn_s_setprio(1);
        #pragma unroll
        for (int m = 0; m < 4; ++m)
            #pragma unroll
            for (int n = 0; n < 2; ++n)
                acc[m][n] = __builtin_amdgcn_mfma_f32_16x16x32_bf16(
                    AH[m], BcH[n], acc[m][n], 0, 0, 0);
        #pragma unroll
        for (int m = 0; m < 4; ++m)
            #pragma unroll
            for (int n = 0; n < 2; ++n)
                acc[m][n] = __builtin_amdgcn_mfma_f32_16x16x32_bf16(
                    AL[m], BcH[n], acc[m][n], 0, 0, 0);
        #pragma unroll
        for (int m = 0; m < 4; ++m)
            #pragma unroll
            for (int n = 0; n < 2; ++n)
                acc[m][n] = __builtin_amdgcn_mfma_f32_16x16x32_bf16(
                    AH[m], BcL[n], acc[m][n], 0, 0, 0);
        __builtin_amdgcn_s_setprio(0);

        // ---------- sub 1: chunk 2it+1 (A half 1, B = Bn) ----------
        #pragma unroll
        for (int m = 0; m < 4; ++m) {
            const int ad = 4096 + lk * 512 + (m * 16 + l15) * 8;
            AH[m] = *(const bf16x8*)&As[cur][ad];
            AL[m] = *(const bf16x8*)&As[cur][2048 + ad];
        }
        {
            const int nc = (it < 7) ? it * 2 + 2 : 15;
            const unsigned short* bp = bslab + (size_t)nc * 16384;
            #pragma unroll
            for (int n = 0; n < 2; ++n) {
                BcH[n] = *(const bf16x8*)(bp + bco + n * 128);
                BcL[n] = *(const bf16x8*)(bp + 8192 + bco + n * 128);
            }
        }
        __builtin_amdgcn_s_setprio(1);
        #pragma unroll
        for (int m = 0; m < 4; ++m)
            #pragma unroll
            for (int n = 0; n < 2; ++n)
                acc[m][n] = __builtin_amdgcn_mfma_f32_16x16x32_bf16(
                    AH[m], BnH[n], acc[m][n], 0, 0, 0);
        #pragma unroll
        for (int m = 0; m < 4; ++m)
            #pragma unroll
            for (int n = 0; n < 2; ++n)
                acc[m][n] = __builtin_amdgcn_mfma_f32_16x16x32_bf16(
                    AL[m], BnH[n], acc[m][n], 0, 0, 0);
        #pragma unroll
        for (int m = 0; m < 4; ++m)
            #pragma unroll
            for (int n = 0; n < 2; ++n)
                acc[m][n] = __builtin_amdgcn_mfma_f32_16x16x32_bf16(
                    AH[m], BnL[n], acc[m][n], 0, 0, 0);
        __builtin_amdgcn_s_setprio(0);

        computeA((it < 7) ? it + 1 : 7, cur ^ 1);
        __syncthreads();
        cur ^= 1;
    }

    // epilogue
    float qp[4][4];
    #pragma unroll
    for (int m = 0; m < 4; ++m)
        #pragma unroll
        for (int r = 0; r < 4; ++r) qp[m][r] = 0.f;
    #pragma unroll
    for (int n = 0; n < 2; ++n) {
        int gcol = cb * 256 + wv * 32 + n * 16 + l15;
        float b2v = b2[h * HID + gcol];
        float w3v = W3[h * HID + gcol];
        #pragma unroll
        for (int m = 0; m < 4; ++m)
            #pragma unroll
            for (int r = 0; r < 4; ++r)
                qp[m][r] += fmaxf(acc[m][n][r] + b2v, 0.f) * w3v;
    }
    #pragma unroll
    for (int m = 0; m < 4; ++m)
        #pragma unroll
        for (int r = 0; r < 4; ++r) {
            float v = qp[m][r];
            v += __shfl_xor(v, 1);
            v += __shfl_xor(v, 2);
            v += __shfl_xor(v, 4);
            v += __shfl_xor(v, 8);
            if (l15 == 0) red[wv][m * 16 + lk * 4 + r] = v;
        }
    __syncthreads();
    if (tid < 64) {
        float q = 0.f;
        #pragma unroll
        for (int s = 0; s < 8; ++s) q += red[s][tid];
        ws[WS_Q + (size_t)(cb * HEADS + h) * POP + rs * 64 + tid] = q;
    }
}

// ---------------------------------------------------------------------------
// Kernel 2 (fp32 fallback, used only if ws too small): writes part0, zeroes
// part1 so k_select's partial-sum read stays correct.
// ---------------------------------------------------------------------------
__global__ __launch_bounds__(256) void k_score(const float* __restrict__ noise,
                                               const float* __restrict__ W1,
                                               const float* __restrict__ W2,
                                               const float* __restrict__ b2,
                                               const float* __restrict__ W3,
                                               float* __restrict__ ws, int t)
{
    __shared__ float h1[32][HID];
    __shared__ float a0s[32], a1s[32];
    __shared__ float red[2][16][2];

    const int tid = threadIdx.x;
    const int h   = blockIdx.y;
    const int p0  = blockIdx.x * 32;

    if (tid < 32) {
        const float* st = ws + WS_STATE;
        const int p = p0 + tid;
        float e0 = noise[((size_t)t * POP + p) * 2 + 0];
        float e1 = noise[((size_t)t * POP + p) * 2 + 1];
        a0s[tid] = fminf(fmaxf(st[0] + st[2] * e0, -1.f), 1.f);
        a1s[tid] = fminf(fmaxf(st[1] + st[3] * e1, -1.f), 1.f);
    }
    __syncthreads();

    const float* base1 = ws + WS_BASE1 + h * HID;
    const float* w1u = W1 + ((size_t)h * 258 + 256) * HID;
    const float* w1v = W1 + ((size_t)h * 258 + 257) * HID;
    #pragma unroll
    for (int jj = 0; jj < 2; ++jj) {
        int j = tid + jj * 256;
        float bb = base1[j], uu = w1u[j], vv = w1v[j];
        #pragma unroll
        for (int p = 0; p < 32; ++p)
            h1[p][j] = fmaxf(bb + a0s[p] * uu + a1s[p] * vv, 0.f);
    }
    __syncthreads();

    const int pg = tid >> 7;
    const int kl = tid & 127;
    const float* W2h = W2 + (size_t)h * HID * HID + kl;

    float acc[16][4];
    #pragma unroll
    for (int p = 0; p < 16; ++p)
        #pragma unroll
        for (int dk = 0; dk < 4; ++dk) acc[p][dk] = 0.f;

    for (int j0 = 0; j0 < HID; j0 += 4) {
        float w[4][4];
        #pragma unroll
        for (int dj = 0; dj < 4; ++dj)
            #pragma unroll
            for (int dk = 0; dk < 4; ++dk)
                w[dj][dk] = W2h[(size_t)(j0 + dj) * HID + dk * 128];
        #pragma unroll
        for (int p = 0; p < 16; ++p) {
            const float4 hv = *(const float4*)&h1[pg * 16 + p][j0];
            #pragma unroll
            for (int dk = 0; dk < 4; ++dk)
                acc[p][dk] += hv.x * w[0][dk] + hv.y * w[1][dk]
                            + hv.z * w[2][dk] + hv.w * w[3][dk];
        }
    }

    float b2v[4], w3v[4];
    #pragma unroll
    for (int dk = 0; dk < 4; ++dk) {
        b2v[dk] = b2[h * HID + kl + dk * 128];
        w3v[dk] = W3[h * HID + kl + dk * 128];
    }
    const int wid  = tid >> 6;
    const int lane = tid & 63;
    const int wig  = wid & 1;
    #pragma unroll
    for (int p = 0; p < 16; ++p) {
        float v = 0.f;
        #pragma unroll
        for (int dk = 0; dk < 4; ++dk)
            v += fmaxf(acc[p][dk] + b2v[dk], 0.f) * w3v[dk];
        #pragma unroll
        for (int off = 32; off; off >>= 1) v += __shfl_down(v, off);
        if (lane == 0) red[pg][p][wig] = v;
    }
    __syncthreads();
    if (tid < 32) {
        int pp = tid & 15, g = tid >> 4;
        ws[WS_Q + (size_t)h * POP + p0 + g * 16 + pp] =
            red[g][pp][0] + red[g][pp][1];
        ws[WS_Q + (size_t)(HEADS + h) * POP + p0 + g * 16 + pp] = 0.f;
    }
}

// ---------------------------------------------------------------------------
// Kernel 3 (1024 threads, barrier-minimal): scores from 2 q partials (+b3),
// exact top-819 radix select, elite mean/std (ddof=1), best_a update.
// Wave-shuffle reductions/scans replace LDS tree scans: ~13 barriers
// (was ~150 -> the kernel was barrier-latency-bound at ~12 us).
// ---------------------------------------------------------------------------
__global__ __launch_bounds__(1024) void k_select(const float* __restrict__ noise,
                                                 const float* __restrict__ b3,
                                                 float* __restrict__ ws,
                                                 float* __restrict__ out, int t)
{
    __shared__ float    sc[POP];        // 16 KB
    __shared__ unsigned uk[POP];        // 16 KB
    __shared__ unsigned hist4[1024];    // 4 radix passes x 256 bins
    __shared__ float    rfW[16];
    __shared__ int      riW[16];
    __shared__ int      waveTot[16];
    __shared__ int      waveExcl[16];
    __shared__ double   wsum[16][4];
    __shared__ unsigned s_prefix;
    __shared__ int      s_r;

    const int tid = threadIdx.x;
    const int lane = tid & 63;
    const int wid = tid >> 6;
    const float* q = ws + WS_Q;
    float* st = ws + WS_STATE;
    const float mu0 = st[0], mu1 = st[1], sd0 = st[2], sd1 = st[3];

    hist4[tid] = 0;

    // scores = mean_h min(q1,q2); q[h] = part0 + part1 + b3[h]
    {
        const int p = tid * 4;
        f32x4 s = (f32x4){0.f, 0.f, 0.f, 0.f};
        #pragma unroll
        for (int hh = 0; hh < NH; ++hh) {
            f32x4 qa0 = *(const f32x4*)&q[(size_t)hh * POP + p];
            f32x4 qa1 = *(const f32x4*)&q[(size_t)(HEADS + hh) * POP + p];
            f32x4 qb0 = *(const f32x4*)&q[(size_t)(NH + hh) * POP + p];
            f32x4 qb1 = *(const f32x4*)&q[(size_t)(HEADS + NH + hh) * POP + p];
            float ba = b3[hh], bb = b3[NH + hh];
            #pragma unroll
            for (int i = 0; i < 4; ++i)
                s[i] += fminf(qa0[i] + qa1[i] + ba, qb0[i] + qb1[i] + bb);
        }
        #pragma unroll
        for (int i = 0; i < 4; ++i) {
            float v = s[i] * 0.2f;
            sc[p + i] = v;
            unsigned b = __float_as_uint(v);
            uk[p + i] = (b & 0x80000000u) ? ~b : (b | 0x80000000u);
        }
    }
    __syncthreads();                                   // B1

    // ---- argmax (lowest index on ties), wave-shuffle butterfly ----
    float mv = -3.402823466e38f; int mi = 0x7FFFFFFF;
    #pragma unroll
    for (int k = 0; k < 4; ++k) {
        const int p = tid * 4 + k;
        float v = sc[p];
        if (v > mv) { mv = v; mi = p; }                // ascending p: > keeps lowest
    }
    #pragma unroll
    for (int off = 1; off < 64; off <<= 1) {
        float ov = __shfl_xor(mv, off);
        int   oi = __shfl_xor(mi, off);
        if (ov > mv || (ov == mv && oi < mi)) { mv = ov; mi = oi; }
    }
    if (lane == 0) { rfW[wid] = mv; riW[wid] = mi; }
    __syncthreads();                                   // B2
    float maxsc = 0.f; int argmax = 0;
    if (wid == 0) {
        float v = (lane < 16) ? rfW[lane] : -3.402823466e38f;
        int   i = (lane < 16) ? riW[lane] : 0x7FFFFFFF;
        #pragma unroll
        for (int off = 1; off < 16; off <<= 1) {
            float ov = __shfl_xor(v, off);
            int   oi = __shfl_xor(i, off);
            if (ov > v || (ov == v && oi < i)) { v = ov; i = oi; }
        }
        maxsc = v; argmax = i;                         // live in wave-0 regs
    }

    // ---- radix select: 4 passes, single-wave suffix-scan digit pick ----
    unsigned prefix = 0; int r = ELITE;
    #pragma unroll 1
    for (int pass = 0; pass < 4; ++pass) {
        const int shift = 24 - pass * 8;
        unsigned* hist = &hist4[pass * 256];
        const unsigned himask = (shift < 24) ? (0xFFFFFFFFu << (shift + 8)) : 0u;
        #pragma unroll
        for (int g = 0; g < 4; ++g) {
            unsigned key = uk[g * 1024 + tid];
            if ((key & himask) == prefix)
                atomicAdd(&hist[(key >> shift) & 255u], 1u);
        }
        __syncthreads();                               // hist done
        if (wid == 0) {
            int h0 = (int)hist[lane * 4 + 0];
            int h1 = (int)hist[lane * 4 + 1];
            int h2 = (int)hist[lane * 4 + 2];
            int h3 = (int)hist[lane * 4 + 3];
            int S = h0 + h1 + h2 + h3;
            #pragma unroll
            for (int off = 1; off < 64; off <<= 1) {
                int tS = __shfl_down(S, off);
                if (lane + off < 64) S += tS;
            }
            int SnRaw = __shfl_down(S, 1);
            int Snext = (lane == 63) ? 0 : SnRaw;      // suffix from lane+1
            int cg1 = S - h0;
            int cg2 = cg1 - h1;
            int cg3 = cg2 - h2;
            // boundary digit d: cnt_ge(d) >= r > cnt_ge(d+1)
            if (S >= r && cg1 < r)        { s_prefix = prefix | ((unsigned)(4 * lane + 0) << shift); s_r = r - cg1; }
            else if (cg1 >= r && cg2 < r) { s_prefix = prefix | ((unsigned)(4 * lane + 1) << shift); s_r = r - cg2; }
            else if (cg2 >= r && cg3 < r) { s_prefix = prefix | ((unsigned)(4 * lane + 2) << shift); s_r = r - cg3; }
            else if (cg3 >= r && Snext < r) { s_prefix = prefix | ((unsigned)(4 * lane + 3) << shift); s_r = r - Snext; }
        }
        __syncthreads();                               // pick done
        prefix = s_prefix; r = s_r;
    }
    const unsigned uT = prefix;
    const int take = r;

    // ---- tie ranks (index order): wave shfl_up scan + 16-entry scan ----
    int tieloc = 0;
    {
        const int base = tid * 4;
        #pragma unroll
        for (int k = 0; k < 4; ++k) if (uk[base + k] == uT) tieloc++;
    }
    int scv = tieloc;
    #pragma unroll
    for (int off = 1; off < 64; off <<= 1) {
        int tv = __shfl_up(scv, off);
        if (lane >= off) scv += tv;
    }
    if (lane == 63) waveTot[wid] = scv;
    __syncthreads();                                   // totals ready
    if (tid == 0) {
        int acc = 0;
        #pragma unroll
        for (int w2 = 0; w2 < 16; ++w2) { waveExcl[w2] = acc; acc += waveTot[w2]; }
    }
    __syncthreads();                                   // excl ready
    const int tieExcl = waveExcl[wid] + (scv - tieloc);

    // ---- elite sums (recompute actions), wave double-shuffle reduce ----
    double s0 = 0, s1 = 0, ss0 = 0, ss1 = 0;
    {
        const int base = tid * 4;
        int trank = tieExcl;
        #pragma unroll
        for (int k = 0; k < 4; ++k) {
            const int p = base + k;
            const unsigned key = uk[p];
            bool inc = false;
            if (key > uT) inc = true;
            else if (key == uT) { if (trank < take) inc = true; trank++; }
            if (inc) {
                float e0 = noise[((size_t)t * POP + p) * 2 + 0];
                float e1 = noise[((size_t)t * POP + p) * 2 + 1];
                float a0 = fminf(fmaxf(mu0 + sd0 * e0, -1.f), 1.f);
                float a1 = fminf(fmaxf(mu1 + sd1 * e1, -1.f), 1.f);
                s0 += a0; s1 += a1;
                ss0 += (double)a0 * a0; ss1 += (double)a1 * a1;
            }
        }
    }
    #pragma unroll
    for (int off = 1; off < 64; off <<= 1) {
        s0 += __shfl_xor(s0, off);
        s1 += __shfl_xor(s1, off);
        ss0 += __shfl_xor(ss0, off);
        ss1 += __shfl_xor(ss1, off);
    }
    if (lane == 0) {
        wsum[wid][0] = s0; wsum[wid][1] = s1;
        wsum[wid][2] = ss0; wsum[wid][3] = ss1;
    }
    __syncthreads();                                   // partials ready

    if (tid == 0) {
        double S0 = 0, S1 = 0, SS0 = 0, SS1 = 0;
        #pragma unroll
        for (int w2 = 0; w2 < 16; ++w2) {
            S0 += wsum[w2][0]; S1 += wsum[w2][1];
            SS0 += wsum[w2][2]; SS1 += wsum[w2][3];
        }
        const double n = (double)ELITE;
        double m0 = S0 / n, m1 = S1 / n;
        double v0 = (SS0 - S0 * S0 / n) / (n - 1.0);
        double v1 = (SS1 - S1 * S1 / n) / (n - 1.0);
        float nsd0 = fmaxf((float)sqrt(fmax(v0, 0.0)), MIN_STDF);
        float nsd1 = fmaxf((float)sqrt(fmax(v1, 0.0)), MIN_STDF);
        float e0 = noise[((size_t)t * POP + argmax) * 2 + 0];
        float e1 = noise[((size_t)t * POP + argmax) * 2 + 1];
        float a0 = fminf(fmaxf(mu0 + sd0 * e0, -1.f), 1.f);
        float a1 = fminf(fmaxf(mu1 + sd1 * e1, -1.f), 1.f);
        if (maxsc > st[6]) { st[4] = a0; st[5] = a1; st[6] = maxsc; }
        st[0] = (float)m0; st[1] = (float)m1; st[2] = nsd0; st[3] = nsd1;
        if (t == ITERS - 1) { out[0] = st[4]; out[1] = st[5]; }
    }
}

// ---------------------------------------------------------------------------
extern "C" void kernel_launch(void* const* d_in, const int* in_sizes, int n_in,
                              void* d_out, int out_size, void* d_ws, size_t ws_size,
                              hipStream_t stream)
{
    const float* state = (const float*)d_in[0];
    const float* noise = (const float*)d_in[1];
    const float* W1    = (const float*)d_in[2];
    const float* b1    = (const float*)d_in[3];
    const float* W2    = (const float*)d_in[4];
    const float* b2    = (const float*)d_in[5];
    const float* W3    = (const float*)d_in[6];
    const float* b3    = (const float*)d_in[7];
    float* out = (float*)d_out;
    float* ws  = (float*)d_ws;

    const bool fast = ws_size >= WS_NEED_BYTES;

    k_base<<<dim3(2, HEADS), 256, 0, stream>>>(state, W1, b1, ws);
    if (fast) {
        unsigned short* W2S = (unsigned short*)((char*)d_ws + WS_W2S_BYTE);
        k_split<<<dim3(16, 2, HEADS), 256, 0, stream>>>(W2, W2S);
        for (int t = 0; t < ITERS; ++t) {
            k_score_mfma13<<<dim3(1280), 512, 0, stream>>>(
                noise, W1, W2S, b2, W3, ws, t);
            k_select<<<1, 1024, 0, stream>>>(noise, b3, ws, out, t);
        }
    } else {
        for (int t = 0; t < ITERS; ++t) {
            k_score<<<dim3(POP / 32, HEADS), 256, 0, stream>>>(noise, W1, W2, b2, W3, ws, t);
            k_select<<<1, 1024, 0, stream>>>(noise, b3, ws, out, t);
        }
    }
}